// Round 3
// baseline (717.028 us; speedup 1.0000x reference)
//
#include <hip/hip_runtime.h>

// Problem constants
#define D_MODEL 256
#define ARITY   32
#define MAXDEP  15
#define VOCABN  1027
#define BATCH   8192
#define KTOT    8192      // 32 children * 256
#define KQ      2048      // K quarter (8 children)
#define LN_EPS  1e-5f

// ---- workspace layout (float offsets) ----
// total bytes needed = 39,324,672 (~37.5 MiB)
#define WS_CIDXP 0         // 32*256: per-child partial of (idx_emb[a]@W_ie_a) + b
#define WS_TOP   8192      // 1027*256: token_emb @ W_op
#define WS_TDEP  271104    // 32*15*256: depth tables
#define WS_PART  393984    // 4*8192*256: GEMM K-quarter partials
#define WS_WT    8782592   // ushort bf16 Wt[256][8192] (ce weights, transposed)

typedef __attribute__((ext_vector_type(4))) float f32x4;
typedef __attribute__((ext_vector_type(8))) short bf16x8;

__device__ __forceinline__ unsigned int f2bf(float f) {
  unsigned int u = __builtin_bit_cast(unsigned int, f);
  return (u + 0x7fffu + ((u >> 16) & 1u)) >> 16;  // RNE, low 16 bits valid
}

// =====================================================================
// K0: build tables (T_op, T_dep, c_idx partials) + transpose ce-weights
// to bf16 Wt[n][k].  W row blocks: e_op rows [0,256); child a: ce rows
// 256+768a, de rows 512+768a, ie rows 768+768a (each 256 rows).
// =====================================================================
__global__ __launch_bounds__(256) void build_tables(
    const float* __restrict__ te, const float* __restrict__ de,
    const float* __restrict__ ie, const float* __restrict__ W,
    const float* __restrict__ bvec, float* __restrict__ ws) {
  __shared__ float sh[4352];
  int bid = blockIdx.x, tid = threadIdx.x;

  if (bid < 257) {  // ---- T_op: 4 vocab rows per WG ----
    int v0 = bid * 4;
    int cnt = VOCABN - v0; if (cnt > 4) cnt = 4;
    for (int j = 0; j < cnt; ++j) sh[j * 256 + tid] = te[(v0 + j) * 256 + tid];
    for (int j = cnt; j < 4; ++j) sh[j * 256 + tid] = 0.f;
    __syncthreads();
    float a0 = 0.f, a1 = 0.f, a2 = 0.f, a3 = 0.f;
#pragma unroll 8
    for (int k = 0; k < 256; ++k) {
      float wv = W[k * 256 + tid];
      a0 += sh[k] * wv;
      a1 += sh[256 + k] * wv;
      a2 += sh[512 + k] * wv;
      a3 += sh[768 + k] * wv;
    }
    float a4[4] = {a0, a1, a2, a3};
    for (int j = 0; j < cnt; ++j) ws[WS_TOP + (v0 + j) * 256 + tid] = a4[j];

  } else if (bid < 289) {  // ---- T_dep: all 15 depths for one child a ----
    int a = bid - 257;
    for (int d = 0; d < MAXDEP; ++d) sh[d * 256 + tid] = de[d * 256 + tid];
    __syncthreads();
    float acc[MAXDEP];
#pragma unroll
    for (int d = 0; d < MAXDEP; ++d) acc[d] = 0.f;
    const float* Wb = W + ((size_t)(512 + 768 * a)) * 256;
#pragma unroll 2
    for (int k = 0; k < 256; ++k) {
      float wv = Wb[(size_t)k * 256 + tid];
#pragma unroll
      for (int d = 0; d < MAXDEP; ++d) acc[d] += sh[d * 256 + k] * wv;
    }
    for (int d = 0; d < MAXDEP; ++d)
      ws[WS_TDEP + (a * MAXDEP + d) * 256 + tid] = acc[d];

  } else if (bid < 321) {  // ---- c_idx partial for one child a (+bias at a==0) ----
    int a = bid - 289;
    sh[tid] = ie[a * 256 + tid];
    __syncthreads();
    float acc = (a == 0) ? bvec[tid] : 0.f;
    const float* Wb = W + ((size_t)(768 + 768 * a)) * 256;
#pragma unroll 8
    for (int k = 0; k < 256; ++k) acc += sh[k] * Wb[(size_t)k * 256 + tid];
    ws[WS_CIDXP + a * 256 + tid] = acc;

  } else {  // ---- Wt transpose tiles: 64k x 64n per WG ----
    int j = bid - 321;            // 0..511
    int kt = j >> 2, nt = j & 3;
    int kr = tid >> 2, q = tid & 3;
    int kk = kt * 64 + kr;
    int a = kk >> 8, kp = kk & 255;
    const float* src = W + ((size_t)(256 + 768 * a + kp)) * 256 + nt * 64 + q * 16;
    float4 v0 = *(const float4*)(src);
    float4 v1 = *(const float4*)(src + 4);
    float4 v2 = *(const float4*)(src + 8);
    float4 v3 = *(const float4*)(src + 12);
    float* row = sh + kr * 68 + q * 16;   // pad 68 keeps float4 alignment
    *(float4*)(row) = v0; *(float4*)(row + 4) = v1;
    *(float4*)(row + 8) = v2; *(float4*)(row + 12) = v3;
    __syncthreads();
    int nl = tid >> 2, c = tid & 3;
#define PK(i) (f2bf(sh[(c * 16 + 2 * (i)) * 68 + nl]) | (f2bf(sh[(c * 16 + 2 * (i) + 1) * 68 + nl]) << 16))
    uint4 u0 = make_uint4(PK(0), PK(1), PK(2), PK(3));
    uint4 u1 = make_uint4(PK(4), PK(5), PK(6), PK(7));
#undef PK
    unsigned short* Wt = (unsigned short*)(ws + WS_WT);
    unsigned short* dst = Wt + (size_t)(nt * 64 + nl) * KTOT + kt * 64 + c * 16;
    *(uint4*)(dst) = u0;
    *(uint4*)(dst + 8) = u1;
  }
}

// =====================================================================
// K1: barrier-free bf16 MFMA GEMM over the child_embs blocks.
// grid = 1024 blocks (256 mt x 4 kq, XCD-affine remap: kq pinned to an
// XCD pair so its 1 MiB Wt quarter stays L2-resident).
// block = 256 (4 waves); wave = n-quadrant, tile 32m x 64n, K=2048.
// No LDS, no __syncthreads: A and W load straight into MFMA fragment
// layout (A f32->bf16 in-reg); named double banks give 1-step lookahead.
// A-sharing across the 4 waves rides on L1 (identical addresses).
// =====================================================================
__global__ void gemm_ce(const float* __restrict__ ce, float* __restrict__ ws) {
  const unsigned short* Wt = (const unsigned short*)(ws + WS_WT);
  float* part = ws + WS_PART;

  int bid = blockIdx.x;
  int kq = (bid >> 1) & 3;                    // XCD pair (bid&7)>>1 owns kq
  int mt = (bid >> 3) + ((bid & 1) << 7);     // bijective: covers 0..255
  int m0 = mt * 32;
  int tid = threadIdx.x;
  int lane = tid & 63, wn = tid >> 6;
  int r15 = lane & 15, g4 = lane >> 4;        // g4 in 0..3
  int klane = g4 * 8;

  // A: rows m0+r15 (+16 for m=1), k = child*256 + s*32 + klane + [0,8)
  const float* pa0 = ce + ((size_t)(kq * 8) * BATCH + m0 + r15) * 256 + klane;
  const float* pa1 = pa0 + (size_t)16 * 256;
  // W: n-row wn*64 + n*16 + r15, same k
  const unsigned short* pwb = Wt + (size_t)(wn * 64 + r15) * KTOT + kq * KQ + klane;
  const unsigned short* pw0 = pwb;
  const unsigned short* pw1 = pwb + (size_t)16 * KTOT;
  const unsigned short* pw2 = pwb + (size_t)32 * KTOT;
  const unsigned short* pw3 = pwb + (size_t)48 * KTOT;

  f32x4 acc[2][4] = {};

  float4 a0loA, a0hiA, a1loA, a1hiA;  uint4 w0A, w1A, w2A, w3A;
  float4 a0loB, a0hiB, a1loB, a1hiB;  uint4 w0B, w1B, w2B, w3B;

#define ISSUE(S, OFF)                                                   \
  a0lo##S = *(const float4*)(pa0 + (OFF));                              \
  a0hi##S = *(const float4*)(pa0 + (OFF) + 4);                          \
  a1lo##S = *(const float4*)(pa1 + (OFF));                              \
  a1hi##S = *(const float4*)(pa1 + (OFF) + 4);                          \
  w0##S = *(const uint4*)(pw0 + (OFF));                                 \
  w1##S = *(const uint4*)(pw1 + (OFF));                                 \
  w2##S = *(const uint4*)(pw2 + (OFF));                                 \
  w3##S = *(const uint4*)(pw3 + (OFF));

#define CVT8(dst, lo, hi) {                                             \
    unsigned q0 = f2bf(lo.x) | (f2bf(lo.y) << 16);                      \
    unsigned q1 = f2bf(lo.z) | (f2bf(lo.w) << 16);                      \
    unsigned q2 = f2bf(hi.x) | (f2bf(hi.y) << 16);                      \
    unsigned q3 = f2bf(hi.z) | (f2bf(hi.w) << 16);                      \
    dst = __builtin_bit_cast(bf16x8, make_uint4(q0, q1, q2, q3)); }

#define COMPUTE(S) {                                                    \
    bf16x8 af0, af1;                                                    \
    CVT8(af0, a0lo##S, a0hi##S);                                        \
    CVT8(af1, a1lo##S, a1hi##S);                                        \
    bf16x8 b0 = __builtin_bit_cast(bf16x8, w0##S);                      \
    bf16x8 b1 = __builtin_bit_cast(bf16x8, w1##S);                      \
    bf16x8 b2 = __builtin_bit_cast(bf16x8, w2##S);                      \
    bf16x8 b3 = __builtin_bit_cast(bf16x8, w3##S);                      \
    acc[0][0] = __builtin_amdgcn_mfma_f32_16x16x32_bf16(af0, b0, acc[0][0], 0, 0, 0); \
    acc[0][1] = __builtin_amdgcn_mfma_f32_16x16x32_bf16(af0, b1, acc[0][1], 0, 0, 0); \
    acc[0][2] = __builtin_amdgcn_mfma_f32_16x16x32_bf16(af0, b2, acc[0][2], 0, 0, 0); \
    acc[0][3] = __builtin_amdgcn_mfma_f32_16x16x32_bf16(af0, b3, acc[0][3], 0, 0, 0); \
    acc[1][0] = __builtin_amdgcn_mfma_f32_16x16x32_bf16(af1, b0, acc[1][0], 0, 0, 0); \
    acc[1][1] = __builtin_amdgcn_mfma_f32_16x16x32_bf16(af1, b1, acc[1][1], 0, 0, 0); \
    acc[1][2] = __builtin_amdgcn_mfma_f32_16x16x32_bf16(af1, b2, acc[1][2], 0, 0, 0); \
    acc[1][3] = __builtin_amdgcn_mfma_f32_16x16x32_bf16(af1, b3, acc[1][3], 0, 0, 0); \
  }

  ISSUE(A, 0);                       // (child 0, step 0)
#pragma unroll 1
  for (int c = 0; c < 8; ++c) {
#pragma unroll
    for (int s = 0; s < 8; s += 2) {
      ISSUE(B, (s + 1) * 32);        // prefetch odd step (always in-child)
      COMPUTE(A);
      if (s == 6) {                  // bump to next child; clamp at last
        size_t ab = (c == 7) ? 0 : (size_t)BATCH * 256;
        size_t wb = (c == 7) ? 0 : 256;
        pa0 += ab; pa1 += ab;
        pw0 += wb; pw1 += wb; pw2 += wb; pw3 += wb;
        ISSUE(A, 0);                 // (c+1, step 0)
      } else {
        ISSUE(A, (s + 2) * 32);
      }
      COMPUTE(B);
    }
  }
#undef ISSUE
#undef CVT8
#undef COMPUTE

  // ---- store partials (C/D layout: col=lane&15, row=(lane>>4)*4+reg) ----
  float* p = part + ((size_t)kq * BATCH + m0) * 256;
#pragma unroll
  for (int m = 0; m < 2; ++m)
#pragma unroll
    for (int n = 0; n < 4; ++n)
#pragma unroll
      for (int r = 0; r < 4; ++r)
        p[(m * 16 + g4 * 4 + r) * 256 + wn * 64 + n * 16 + r15] = acc[m][n][r];
}

// =====================================================================
// K2: partial sum + table gathers + bias/idx const + ReLU + LayerNorm
// grid = 256 WGs x 32 batch rows each.
// =====================================================================
__global__ __launch_bounds__(256) void epilogue(
    const int* __restrict__ nid, const int* __restrict__ cdep,
    const float* __restrict__ ws, const float* __restrict__ lng,
    const float* __restrict__ lnb, float* __restrict__ out) {
  __shared__ float h[32][256];
  __shared__ int cdl[32][32];
  __shared__ int nidl[32];
  int m0 = blockIdx.x * 32, tid = threadIdx.x;
#pragma unroll
  for (int i = 0; i < 4; ++i) {
    int idx = i * 256 + tid;
    int a = idx >> 5, r = idx & 31;
    cdl[r][a] = cdep[a * BATCH + m0 + r];
  }
  if (tid < 32) nidl[tid] = nid[m0 + tid];
  __syncthreads();

  int col = tid;
  float ci = 0.f;
#pragma unroll 8
  for (int a = 0; a < ARITY; ++a) ci += ws[WS_CIDXP + a * 256 + col];

  const float* p0 = ws + WS_PART + (size_t)m0 * 256;
  const float* Top = ws + WS_TOP;
  const float* Td  = ws + WS_TDEP;

  for (int r = 0; r < 32; ++r) {
    float v = ci + Top[(size_t)nidl[r] * 256 + col];
#pragma unroll
    for (int q = 0; q < 4; ++q)
      v += p0[(size_t)q * BATCH * 256 + r * 256 + col];
#pragma unroll
    for (int a = 0; a < ARITY; ++a)
      v += Td[(size_t)(a * MAXDEP + cdl[r][a]) * 256 + col];
    h[r][col] = fmaxf(v, 0.f);
  }
  __syncthreads();

  int lane = tid & 63, w = tid >> 6;
  for (int rr = 0; rr < 8; ++rr) {
    int r = w * 8 + rr;
    float x0 = h[r][lane],       x1 = h[r][64 + lane];
    float x2 = h[r][128 + lane], x3 = h[r][192 + lane];
    float s = x0 + x1 + x2 + x3;
    float q = x0 * x0 + x1 * x1 + x2 * x2 + x3 * x3;
#pragma unroll
    for (int off = 32; off >= 1; off >>= 1) {
      s += __shfl_xor(s, off);
      q += __shfl_xor(q, off);
    }
    float mu = s * (1.f / 256.f);
    float var = q * (1.f / 256.f) - mu * mu;
    float rs = rsqrtf(var + LN_EPS);
    float* o = out + (size_t)(m0 + r) * 256;
    o[lane]       = (x0 - mu) * rs * lng[lane]       + lnb[lane];
    o[64 + lane]  = (x1 - mu) * rs * lng[64 + lane]  + lnb[64 + lane];
    o[128 + lane] = (x2 - mu) * rs * lng[128 + lane] + lnb[128 + lane];
    o[192 + lane] = (x3 - mu) * rs * lng[192 + lane] + lnb[192 + lane];
  }
}

extern "C" void kernel_launch(void* const* d_in, const int* in_sizes, int n_in,
                              void* d_out, int out_size, void* d_ws, size_t ws_size,
                              hipStream_t stream) {
  const int*   nid  = (const int*)d_in[0];
  const float* ce   = (const float*)d_in[1];   // child_embs [32][8192][256]
  const int*   cdep = (const int*)d_in[2];     // child_depths [32][8192]
  const float* te   = (const float*)d_in[3];   // token_emb [1027][256]
  const float* de   = (const float*)d_in[4];   // depth_emb [15][256]
  const float* ie   = (const float*)d_in[5];   // idx_emb [32][256]
  const float* W    = (const float*)d_in[6];   // [24832][256]
  const float* bv   = (const float*)d_in[7];
  const float* lng  = (const float*)d_in[8];
  const float* lnb  = (const float*)d_in[9];
  float* out = (float*)d_out;
  float* ws  = (float*)d_ws;   // needs ~37.5 MiB

  build_tables<<<dim3(833), dim3(256), 0, stream>>>(te, de, ie, W, bv, ws);
  gemm_ce<<<dim3(1024), dim3(256), 0, stream>>>(ce, ws);
  epilogue<<<dim3(256), dim3(256), 0, stream>>>(nid, cdep, ws, lng, lnb, out);
}